// Round 3
// baseline (323.045 us; speedup 1.0000x reference)
//
#include <hip/hip_runtime.h>

// SoftTriple loss, MI355X. B=256, E=512, C=8192, K=10.
// FUSED: normalize + gram + GEMM in one kernel. Each block owns 8 classes
// (80 packed W rows). Wave w loads class cb+w fully into registers
// (10 rows x 8 f32/lane), computes inv-norms + gram pairs via butterfly
// shuffles, writes normalized bf16 rows into a PERSISTENT XOR-swizzled
// 80 KB LDS W buffer. K-loop then reads W fragments from LDS (swizzled,
// ds_read_b128 at its 8-cyc floor) and stages only E (16 KB) per K-step.
// fc is read ONCE from HBM; the 84 MB w round-trip is eliminated.
// ws layout (bytes):
//   [0, 262144)         emb_bf16 [256][512]
//   [262144, 8650752)   h float [256][8192]
//   [8650752, 8683520)  gram_part float[8192]
//   [8683520, 8684544)  ce_part  float[256]

typedef __bf16 bf16;
typedef bf16 bf16x8 __attribute__((ext_vector_type(8)));
typedef float f32x4 __attribute__((ext_vector_type(4)));

#define NCLASS 8192
#define KC 10
#define EDIM 512
#define BATCH 256

__device__ inline void load_lds16(const void* g, void* l) {
    __builtin_amdgcn_global_load_lds(
        (const __attribute__((address_space(1))) void*)g,
        (__attribute__((address_space(3))) void*)l, 16, 0, 0);
}

// ---------------- kernel 1: embeddings fp32 -> bf16 -----------------------
__global__ __launch_bounds__(256) void conv_kernel(
    const float* __restrict__ e, bf16* __restrict__ out)
{
    int i = blockIdx.x * 256 + threadIdx.x;   // 64 blocks * 256 * 8 = 131072
    float4 a = ((const float4*)e)[i * 2];
    float4 b = ((const float4*)e)[i * 2 + 1];
    bf16x8 v;
    v[0] = (bf16)a.x; v[1] = (bf16)a.y; v[2] = (bf16)a.z; v[3] = (bf16)a.w;
    v[4] = (bf16)b.x; v[5] = (bf16)b.y; v[6] = (bf16)b.z; v[7] = (bf16)b.w;
    ((bf16x8*)out)[i] = v;
}

// ---------------- kernel 2: fused normalize + gram + GEMM + k-softmax -----
// 512 threads = 8 waves. Phase 1: wave w handles class blockIdx*8+w.
// Phase 2: wave grid 1(m) x 8(n); each wave = all 80 rows x 32 batch cols
// = 5x2 MFMA 16x16x32 tiles. Epilogue: packed row r=16*mt+4*quad+reg,
// class=r/10; per-class softmax via static predicated partials + quad
// shuffles (proven in round 2, absmax 0).
__global__ __launch_bounds__(512, 2) void fused_kernel(
    const float* __restrict__ fc,  // [81920][512] raw centers
    const bf16* __restrict__ A,    // [256][512] emb bf16
    float* __restrict__ h,         // [256][8192]
    float* __restrict__ gram_part) // [8192]
{
    __shared__ bf16 Wl[80 * EDIM]; // 80 KB, row-XOR-swizzled
    __shared__ bf16 Es[256 * 32];  // 16 KB
    const int tid = threadIdx.x;
    const int wave = tid >> 6, lane = tid & 63;

    // ---- phase 1: load class into regs, norms, gram, swizzled LDS write --
    const int c = blockIdx.x * 8 + wave;
    float4 ra[KC][2];              // lane holds elems [lane*8, lane*8+8)
    #pragma unroll
    for (int r = 0; r < KC; ++r) {
        const float4* rp =
            (const float4*)(fc + ((size_t)c * KC + r) * EDIM) + lane * 2;
        ra[r][0] = rp[0];
        ra[r][1] = rp[1];
    }
    float invn[KC];
    #pragma unroll
    for (int r = 0; r < KC; ++r) {
        float4 a = ra[r][0], b = ra[r][1];
        float s = a.x*a.x + a.y*a.y + a.z*a.z + a.w*a.w
                + b.x*b.x + b.y*b.y + b.z*b.z + b.w*b.w;
        #pragma unroll
        for (int off = 32; off; off >>= 1) s += __shfl_xor(s, off);
        invn[r] = 1.0f / fmaxf(sqrtf(s), 1e-12f);
    }
    float part = 0.f;
    #pragma unroll
    for (int i = 0; i < KC - 1; ++i) {
        #pragma unroll
        for (int j = i + 1; j < KC; ++j) {
            float4 ai = ra[i][0], bi = ra[i][1];
            float4 aj = ra[j][0], bj = ra[j][1];
            float s = ai.x*aj.x + ai.y*aj.y + ai.z*aj.z + ai.w*aj.w
                    + bi.x*bj.x + bi.y*bj.y + bi.z*bj.z + bi.w*bj.w;
            #pragma unroll
            for (int off = 32; off; off >>= 1) s += __shfl_xor(s, off);
            float sub = 1.0f - s * invn[i] * invn[j];
            if (sub <= 0.0f) sub = 1e-10f;
            part += sqrtf(2.0f * sub);
        }
    }
    if (lane == 0) gram_part[c] = part;

    // normalized bf16 write: row's 16B chunk lane goes to slot lane^(row&7)
    #pragma unroll
    for (int r = 0; r < KC; ++r) {
        int row = wave * KC + r;          // 0..79 packed LDS row
        float inv = invn[r];
        float4 a = ra[r][0], b = ra[r][1];
        bf16x8 v;
        v[0] = (bf16)(a.x * inv); v[1] = (bf16)(a.y * inv);
        v[2] = (bf16)(a.z * inv); v[3] = (bf16)(a.w * inv);
        v[4] = (bf16)(b.x * inv); v[5] = (bf16)(b.y * inv);
        v[6] = (bf16)(b.z * inv); v[7] = (bf16)(b.w * inv);
        *(bf16x8*)&Wl[row * EDIM + ((lane ^ (row & 7)) << 3)] = v;
    }
    // (first __syncthreads inside the K-loop publishes Wl to all waves)

    // ---- phase 2: GEMM over kb, W resident in LDS ----
    f32x4 acc[5][2];
    #pragma unroll
    for (int mt = 0; mt < 5; ++mt)
        #pragma unroll
        for (int nt = 0; nt < 2; ++nt)
            acc[mt][nt] = (f32x4){0.f, 0.f, 0.f, 0.f};

    const int srow = lane >> 2;          // staging row within 16-row slab
    const int scol = (lane & 3) * 8;     // staging 16B chunk elem offset

    for (int kb = 0; kb < EDIM; kb += 32) {
        #pragma unroll
        for (int p = 0; p < 2; ++p) {
            int row = p * 128 + wave * 16 + srow;
            load_lds16(A + row * EDIM + kb + scol,
                       Es + (p * 128 + wave * 16) * 32);
        }
        __syncthreads();

        const int q8 = (lane >> 4) * 8;
        const int fr = lane & 15;
        bf16x8 wf[5], ef[2];
        #pragma unroll
        for (int mt = 0; mt < 5; ++mt) {
            int row = mt * 16 + fr;
            wf[mt] = *(const bf16x8*)
                &Wl[row * EDIM + ((kb + q8) ^ ((row & 7) << 3))];
        }
        #pragma unroll
        for (int nt = 0; nt < 2; ++nt)
            ef[nt] = *(const bf16x8*)&Es[(wave * 32 + nt * 16 + fr) * 32 + q8];
        #pragma unroll
        for (int mt = 0; mt < 5; ++mt)
            #pragma unroll
            for (int nt = 0; nt < 2; ++nt)
                acc[mt][nt] = __builtin_amdgcn_mfma_f32_16x16x32_bf16(
                    wf[mt], ef[nt], acc[mt][nt], 0, 0, 0);
        __syncthreads();
    }

    // epilogue: packed row r = 16*mt + 4*quad + reg; class c = r/10.
    const int col = lane & 15;
    const int quad = lane >> 4;
    const int cb = blockIdx.x * 8;
    #pragma unroll
    for (int nt = 0; nt < 2; ++nt) {
        int b = wave * 32 + nt * 16 + col;
        float hval[8];
        #pragma unroll
        for (int cc = 0; cc < 8; ++cc) {
            float xm = -1e30f;
            #pragma unroll
            for (int mt = 0; mt < 5; ++mt) {
                if (10 * cc + 10 > 16 * mt && 10 * cc < 16 * mt + 16) { // static
                    #pragma unroll
                    for (int rg = 0; rg < 4; ++rg) {
                        int r = 16 * mt + 4 * quad + rg;
                        if (r >= 10 * cc && r < 10 * cc + 10)          // runtime
                            xm = fmaxf(xm, acc[mt][nt][rg]);
                    }
                }
            }
            xm = fmaxf(xm, __shfl_xor(xm, 16));
            xm = fmaxf(xm, __shfl_xor(xm, 32));
            float s1 = 0.f, s2 = 0.f;
            #pragma unroll
            for (int mt = 0; mt < 5; ++mt) {
                if (10 * cc + 10 > 16 * mt && 10 * cc < 16 * mt + 16) { // static
                    #pragma unroll
                    for (int rg = 0; rg < 4; ++rg) {
                        int r = 16 * mt + 4 * quad + rg;
                        if (r >= 10 * cc && r < 10 * cc + 10) {        // runtime
                            float x = acc[mt][nt][rg];
                            float e = __expf(10.0f * (x - xm));
                            s1 += e; s2 += e * x;
                        }
                    }
                }
            }
            s1 += __shfl_xor(s1, 16); s1 += __shfl_xor(s1, 32);
            s2 += __shfl_xor(s2, 16); s2 += __shfl_xor(s2, 32);
            hval[cc] = s2 / s1;
        }
        if (quad == 0) {
            float4 v0 = {hval[0], hval[1], hval[2], hval[3]};
            float4 v1 = {hval[4], hval[5], hval[6], hval[7]};
            float4* dst = (float4*)&h[(size_t)b * NCLASS + cb];
            dst[0] = v0;
            dst[1] = v1;
        }
    }
}

// ---------------- kernel 3: cross-entropy over 8192 classes per row -------
__global__ __launch_bounds__(256) void ce_kernel(
    const float* __restrict__ h, const int* __restrict__ labels,
    float* __restrict__ ce_part)
{
    __shared__ float redm[4];
    __shared__ float reds[4];
    const int b = blockIdx.x, t = threadIdx.x;
    const int wave = t >> 6, lane = t & 63;
    const int lbl = labels[b];
    const float* hb = h + (size_t)b * NCLASS;

    float lg_cache[32];
    float mx = -1e30f;
    #pragma unroll
    for (int k = 0; k < 32; ++k) {
        int c = t + k * 256;
        float lg = 10.0f * hb[c];
        if (c == lbl) lg -= 0.1f;          // LMD * MARGIN
        lg_cache[k] = lg;
        mx = fmaxf(mx, lg);
    }
    #pragma unroll
    for (int off = 32; off; off >>= 1) mx = fmaxf(mx, __shfl_xor(mx, off));
    if (lane == 0) redm[wave] = mx;
    __syncthreads();
    mx = fmaxf(fmaxf(redm[0], redm[1]), fmaxf(redm[2], redm[3]));

    float s = 0.f;
    #pragma unroll
    for (int k = 0; k < 32; ++k) s += __expf(lg_cache[k] - mx);
    #pragma unroll
    for (int off = 32; off; off >>= 1) s += __shfl_xor(s, off);
    if (lane == 0) reds[wave] = s;
    __syncthreads();
    if (t == 0) {
        s = reds[0] + reds[1] + reds[2] + reds[3];
        float logit_l = 10.0f * (hb[lbl] - 0.01f);
        ce_part[b] = mx + logf(s) - logit_l;   // -logp[label]
    }
}

// ---------------- kernel 4: reduce partials + combine ---------------------
__global__ __launch_bounds__(256) void final_kernel(
    const float* __restrict__ gram_part, const float* __restrict__ ce_part,
    float* __restrict__ out)
{
    __shared__ float red[4];
    const int t = threadIdx.x, wave = t >> 6, lane = t & 63;
    float g = 0.f;
    #pragma unroll
    for (int i = 0; i < 32; ++i) g += gram_part[t + i * 256];
    float val = ce_part[t] * (1.0f / 256.0f)
              + g * (0.2f / 737280.0f);       // C*K*(K-1) = 737280
    #pragma unroll
    for (int off = 32; off; off >>= 1) val += __shfl_xor(val, off);
    if (lane == 0) red[wave] = val;
    __syncthreads();
    if (t == 0) out[0] = red[0] + red[1] + red[2] + red[3];
}

extern "C" void kernel_launch(void* const* d_in, const int* in_sizes, int n_in,
                              void* d_out, int out_size, void* d_ws, size_t ws_size,
                              hipStream_t stream) {
    const float* emb    = (const float*)d_in[0];   // [256][512]
    const int*   labels = (const int*)d_in[1];     // [256]
    const float* fc     = (const float*)d_in[2];   // [81920][512]
    float* out = (float*)d_out;

    char* ws = (char*)d_ws;
    bf16*  embb      = (bf16*)ws;                        //    262144 B
    float* h         = (float*)(ws + 262144);            //   8388608 B
    float* gram_part = (float*)(ws + 8650752);           //     32768 B
    float* ce_part   = (float*)(ws + 8683520);           //      1024 B

    conv_kernel<<<64, 256, 0, stream>>>(emb, embb);
    fused_kernel<<<NCLASS / 8, 512, 0, stream>>>(fc, embb, h, gram_part);
    ce_kernel<<<BATCH, 256, 0, stream>>>(h, labels, ce_part);
    final_kernel<<<1, 256, 0, stream>>>(gram_part, ce_part, out);
}